// Round 5
// baseline (655.090 us; speedup 1.0000x reference)
//
#include <hip/hip_runtime.h>
#include <cstdint>
#include <cstddef>

// ---------------- problem constants ----------------
#define TGT   24
#define BS    16
#define SRC   400
#define VOCABN 32000
#define DIM   256
#define NROW  (TGT*BS)   // 384

typedef __bf16 bf16_t;
typedef __bf16 v8bf __attribute__((ext_vector_type(8)));
typedef float  v4f  __attribute__((ext_vector_type(4)));

// ---------------- prep: dtype conversions / transposes / gather ----------------
__global__ void k_prep(const float* __restrict__ Whh, const float* __restrict__ Wad,
                       const float* __restrict__ he,  const float* __restrict__ Wemb,
                       const float* __restrict__ Wproj, const float* __restrict__ Wae,
                       const float* __restrict__ Wih, const int* __restrict__ inputs,
                       bf16_t* o_whh, bf16_t* o_wadT, bf16_t* o_he, bf16_t* o_heT,
                       bf16_t* o_wae, bf16_t* o_wih, bf16_t* o_wprojT, bf16_t* o_embA)
{
    const long S0=262144, S1=65536, S2=1638400, S3=1638400, S4=65536, S5=262144, S6=196608, S7=98304;
    const long total = S0+S1+S2+S3+S4+S5+S6+S7;
    for (long i = (long)blockIdx.x*blockDim.x + threadIdx.x; i < total;
         i += (long)gridDim.x*blockDim.x) {
        long j = i;
        if (j < S0) { o_whh[j] = (bf16_t)Whh[j]; continue; }           j -= S0;
        if (j < S1) { long n = j>>8, k = j&255; o_wadT[j] = (bf16_t)Wad[k*DIM + n]; continue; } j -= S1;
        if (j < S2) { o_he[j] = (bf16_t)he[j]; continue; }             j -= S2;
        if (j < S3) { // heT[b][d][s] = he[(s*BS+b)*DIM+d]
            long b = j / 102400, rem = j % 102400, d = rem / 400, s = rem % 400;
            o_heT[j] = (bf16_t)he[(s*BS + b)*DIM + d]; continue; }     j -= S3;
        if (j < S4) { o_wae[j] = (bf16_t)Wae[j]; continue; }           j -= S4;
        if (j < S5) { o_wih[j] = (bf16_t)Wih[j]; continue; }           j -= S5;
        if (j < S6) { long n = j>>8, k = j&255; o_wprojT[j] = (bf16_t)Wproj[k*768 + n]; continue; } j -= S6;
        { long r = j>>8, k = j&255; o_embA[j] = (bf16_t)Wemb[(long)inputs[r]*DIM + k]; }
    }
}

// ---------------- GEMM core (device): 128x128 tile, BK=32 ----------------
// C[M,N] = A[M,K] @ B[N,K]^T  (row-major, K-contiguous). A32!=null: A read fp32.
// mode 0: outF = acc+bias0+bias1; 1: outB = bf16(tanh); 2: outB = bf16;
// mode 3: outF = pad? 0 : exp(acc+bias0), + per-row sums into rsum (atomics).
__device__ __forceinline__ void gemm_core(
    const bf16_t* __restrict__ A, const float* __restrict__ A32,
    const bf16_t* __restrict__ B,
    int N, int K, int bid, int Ntiles, int mode,
    float* outF, bf16_t* outB,
    const float* __restrict__ bias0, const float* __restrict__ bias1,
    const int* __restrict__ padp, float* __restrict__ rsum,
    bf16_t* As, bf16_t* Bs)
{
    const int tid  = threadIdx.x;
    const int mt   = bid / Ntiles, nt = bid % Ntiles;
    const int m0   = mt*128, n0 = nt*128;
    const int lane = tid & 63, wave = tid >> 6;
    const int wm   = wave >> 1, wn = wave & 1;
    const int quad = lane >> 4, l16 = lane & 15;

    v4f acc[4][4];
#pragma unroll
    for (int i=0;i<4;i++)
#pragma unroll
        for (int j=0;j<4;j++) acc[i][j] = (v4f){0.f,0.f,0.f,0.f};

    const int srow = tid >> 1, shalf = tid & 1;       // staging: 2 threads/row
    const bf16_t* Ag   = A   ? A   + (size_t)(m0+srow)*K + shalf*16 : nullptr;
    const float*  Ag32 = A32 ? A32 + (size_t)(m0+srow)*K + shalf*16 : nullptr;
    const bf16_t* Bg = B + (size_t)(n0+srow)*K + shalf*16;
    bf16_t* AsW = &As[srow*40 + shalf*16];
    bf16_t* BsW = &Bs[srow*40 + shalf*16];

    for (int kc = 0; kc < K; kc += 32) {
        __syncthreads();
        uint4 b0 = *(const uint4*)(Bg + kc);
        uint4 b1 = *(const uint4*)(Bg + kc + 8);
        if (A32) {
            float4 f0 = *(const float4*)(Ag32 + kc);
            float4 f1 = *(const float4*)(Ag32 + kc + 4);
            float4 f2 = *(const float4*)(Ag32 + kc + 8);
            float4 f3 = *(const float4*)(Ag32 + kc + 12);
            v8bf u0, u1;
            u0[0]=(bf16_t)f0.x; u0[1]=(bf16_t)f0.y; u0[2]=(bf16_t)f0.z; u0[3]=(bf16_t)f0.w;
            u0[4]=(bf16_t)f1.x; u0[5]=(bf16_t)f1.y; u0[6]=(bf16_t)f1.z; u0[7]=(bf16_t)f1.w;
            u1[0]=(bf16_t)f2.x; u1[1]=(bf16_t)f2.y; u1[2]=(bf16_t)f2.z; u1[3]=(bf16_t)f2.w;
            u1[4]=(bf16_t)f3.x; u1[5]=(bf16_t)f3.y; u1[6]=(bf16_t)f3.z; u1[7]=(bf16_t)f3.w;
            *(v8bf*)AsW = u0; *(v8bf*)(AsW+8) = u1;
        } else {
            uint4 a0 = *(const uint4*)(Ag + kc);
            uint4 a1 = *(const uint4*)(Ag + kc + 8);
            *(uint4*)AsW = a0; *(uint4*)(AsW+8) = a1;
        }
        *(uint4*)BsW = b0; *(uint4*)(BsW+8) = b1;
        __syncthreads();
        v8bf af[4], bb[4];
#pragma unroll
        for (int i=0;i<4;i++) {
            af[i] = *(const v8bf*)&As[(wm*64 + i*16 + l16)*40 + quad*8];
            bb[i] = *(const v8bf*)&Bs[(wn*64 + i*16 + l16)*40 + quad*8];
        }
#pragma unroll
        for (int i=0;i<4;i++)
#pragma unroll
            for (int j=0;j<4;j++)
                acc[i][j] = __builtin_amdgcn_mfma_f32_16x16x32_bf16(af[i], bb[j], acc[i][j], 0,0,0);
    }

    const int pad = padp ? *padp : -1;
    float* rs = (float*)As;          // LDS reuse for mode-3 row partial sums
    if (mode == 3) {
        __syncthreads();             // everyone past last As read
        if (tid < 128) rs[tid] = 0.f;
        __syncthreads();
    }
#pragma unroll
    for (int i=0;i<4;i++) {
        float rloc[4] = {0.f,0.f,0.f,0.f};
#pragma unroll
        for (int j=0;j<4;j++) {
#pragma unroll
            for (int r=0;r<4;r++) {
                const int gr = m0 + wm*64 + i*16 + quad*4 + r;   // C/D row = quad*4+reg
                const int gc = n0 + wn*64 + j*16 + l16;          // C/D col = lane&15
                const float v = acc[i][j][r];
                if (mode == 0)      outF[(size_t)gr*N + gc] = v + bias0[gc] + bias1[gc];
                else if (mode == 1) outB[(size_t)gr*N + gc] = (bf16_t)tanhf(v);
                else if (mode == 2) outB[(size_t)gr*N + gc] = (bf16_t)v;
                else {
                    float ex = (gc == pad) ? 0.f : __expf(v + bias0[gc]);
                    outF[(size_t)gr*N + gc] = ex;
                    rloc[r] += ex;
                }
            }
        }
        if (mode == 3) {
#pragma unroll
            for (int r=0;r<4;r++)
                atomicAdd(&rs[wm*64 + i*16 + quad*4 + r], rloc[r]);
        }
    }
    if (mode == 3) {
        __syncthreads();
        if (tid < 128) atomicAdd(&rsum[m0 + tid], rs[tid]);
    }
}

// ---------------- standalone GEMM kernel ----------------
__global__ __launch_bounds__(256) void k_gemm(
    const bf16_t* __restrict__ A, const float* __restrict__ A32,
    const bf16_t* __restrict__ B,
    int N, int K, int Ntiles, int mode,
    float* outF, bf16_t* outB,
    const float* __restrict__ bias0, const float* __restrict__ bias1,
    const int* __restrict__ padp, float* __restrict__ rsum)
{
    __shared__ bf16_t As[128*40];
    __shared__ bf16_t Bs[128*40];
    gemm_core(A, A32, B, N, K, blockIdx.x, Ntiles, mode,
              outF, outB, bias0, bias1, padp, rsum, As, Bs);
}

// ---------------- LSTM path (device, 256 threads): weight-resident ----------------
// 4 waves, 1/SIMD, 512-VGPR cap. Wave w owns gate-rows g*256 + w*64 + [0,64) for
// g=0..3 (4 n-tiles each). Gates 0..2 weights -> 384 VGPR; gate 3 -> 128 KB LDS.
// A = h as hi+lo bf16. C row = b (quad*4+r), C col = d-in-tile (lane&15).
__device__ void lstm_path(
    const bf16_t* __restrict__ Whh, const float* __restrict__ xg,
    const float* __restrict__ h0, const float* __restrict__ c0,
    float* __restrict__ hallF, bf16_t* __restrict__ hallB, char* smem)
{
    bf16_t* wlds = (bf16_t*)smem;                            // 131072 B
    bf16_t (*hhi)[264] = (bf16_t(*)[264])(smem + 131072);    // 8448 B
    bf16_t (*hlo)[264] = (bf16_t(*)[264])(smem + 139520);    // 8448 B

    const int tid = threadIdx.x;
    const int w = tid >> 6, lane = tid & 63;
    const int l16 = lane & 15, quad = lane >> 4;

    // stage gate-3 (rows 768..1023) into LDS: entry ((wv*4+tt)*8+kc)*64+lane -> 16B
    for (int idx = tid; idx < 8192; idx += 256) {
        int lane2 = idx & 63, kc = (idx >> 6) & 7, tt = (idx >> 9) & 3, wv = idx >> 11;
        int row = 768 + wv*64 + tt*16 + (lane2 & 15);
        *(uint4*)&wlds[idx*8] = *(const uint4*)&Whh[(size_t)row*DIM + kc*32 + (lane2>>4)*8];
    }
    // gates 0..2 into registers: wreg[g][tt][kc]
    v8bf wreg[3][4][8];
#pragma unroll
    for (int g = 0; g < 3; ++g)
#pragma unroll
      for (int tt = 0; tt < 4; ++tt)
#pragma unroll
        for (int kc = 0; kc < 8; ++kc)
            wreg[g][tt][kc] = *(const v8bf*)&Whh[(size_t)(g*256 + w*64 + tt*16 + l16)*DIM + kc*32 + quad*8];

    for (int i = tid; i < 4096; i += 256) {
        int b = i >> 8, d = i & 255;
        float v = h0[b*DIM + d];
        bf16_t hi = (bf16_t)v;
        hhi[b][d] = hi; hlo[b][d] = (bf16_t)(v - (float)hi);
    }
    float c[4][4];
#pragma unroll
    for (int tt = 0; tt < 4; ++tt)
#pragma unroll
      for (int r = 0; r < 4; ++r)
        c[tt][r] = c0[(quad*4 + r)*DIM + w*64 + tt*16 + l16];
    __syncthreads();

    for (int step = 0; step < TGT; ++step) {
        v4f acc[4][4];   // [gate][tt]
#pragma unroll
        for (int g = 0; g < 4; ++g)
#pragma unroll
          for (int tt = 0; tt < 4; ++tt) acc[g][tt] = (v4f){0.f,0.f,0.f,0.f};

#pragma unroll
        for (int kc = 0; kc < 8; ++kc) {
            v8bf ahi = *(const v8bf*)&hhi[l16][kc*32 + quad*8];
            v8bf alo = *(const v8bf*)&hlo[l16][kc*32 + quad*8];
#pragma unroll
            for (int g = 0; g < 3; ++g)
#pragma unroll
              for (int tt = 0; tt < 4; ++tt) {
                acc[g][tt] = __builtin_amdgcn_mfma_f32_16x16x32_bf16(ahi, wreg[g][tt][kc], acc[g][tt], 0,0,0);
                acc[g][tt] = __builtin_amdgcn_mfma_f32_16x16x32_bf16(alo, wreg[g][tt][kc], acc[g][tt], 0,0,0);
              }
#pragma unroll
            for (int tt = 0; tt < 4; ++tt) {
                v8bf bl = *(const v8bf*)&wlds[((((w*4+tt)*8) + kc)*64 + lane)*8];
                acc[3][tt] = __builtin_amdgcn_mfma_f32_16x16x32_bf16(ahi, bl, acc[3][tt], 0,0,0);
                acc[3][tt] = __builtin_amdgcn_mfma_f32_16x16x32_bf16(alo, bl, acc[3][tt], 0,0,0);
            }
        }
        __syncthreads();   // all reads of old h complete
        const float* xgp = xg + (size_t)step*BS*1024;
#pragma unroll
        for (int tt = 0; tt < 4; ++tt) {
            const int d = w*64 + tt*16 + l16;
#pragma unroll
            for (int r = 0; r < 4; ++r) {
                const int b = quad*4 + r;
                const float* xb = xgp + b*1024 + d;
                const float gi = acc[0][tt][r] + xb[0];
                const float gf = acc[1][tt][r] + xb[256];
                const float gg = acc[2][tt][r] + xb[512];
                const float go = acc[3][tt][r] + xb[768];
                const float si = 1.f/(1.f+__expf(-gi));
                const float sf = 1.f/(1.f+__expf(-gf));
                const float so = 1.f/(1.f+__expf(-go));
                const float cn = sf*c[tt][r] + si*tanhf(gg);
                const float hn = so*tanhf(cn);
                c[tt][r] = cn;
                const bf16_t hi = (bf16_t)hn;
                hhi[b][d] = hi; hlo[b][d] = (bf16_t)(hn - (float)hi);
                hallF[(size_t)(step*BS + b)*DIM + d] = hn;
                hallB[(size_t)(step*BS + b)*DIM + d] = hi;
            }
        }
        __syncthreads();
    }
}

// ---------------- fused: block 0 = LSTM; 1..1500 = W_out GEMM; 1501..1600 = ke ---
__global__ __launch_bounds__(256, 1) void k_fused(
    const bf16_t* __restrict__ Whh, const float* __restrict__ xg,
    const float* __restrict__ h0, const float* __restrict__ c0,
    float* __restrict__ hallF, bf16_t* __restrict__ hallB,
    const float* __restrict__ Wemb, const bf16_t* __restrict__ wprojT,
    bf16_t* __restrict__ wout,
    const bf16_t* __restrict__ hebf, const bf16_t* __restrict__ wae,
    bf16_t* __restrict__ ke)
{
    __shared__ char smem[147968];
    if (blockIdx.x == 0) {
        lstm_path(Whh, xg, h0, c0, hallF, hallB, smem);
    } else if (blockIdx.x <= 1500) {
        // W_out = tanh(W_emb @ W_proj) : M=32000, N=768, K=256, mode 1
        gemm_core(nullptr, Wemb, wprojT, 768, 256, blockIdx.x - 1, 6, 1,
                  nullptr, wout, nullptr, nullptr, nullptr, nullptr,
                  (bf16_t*)smem, (bf16_t*)(smem + 10240));
    } else {
        // ke = h_e @ W_ae^T : M=6400, N=256, K=256, mode 2
        gemm_core(hebf, nullptr, wae, 256, 256, blockIdx.x - 1501, 2, 2,
                  nullptr, ke, nullptr, nullptr, nullptr, nullptr,
                  (bf16_t*)smem, (bf16_t*)(smem + 10240));
    }
}

// ---------------- expE[t,b,s] = exp(ke[s,b,:] . h[t,b,:]) — fully parallel ------
__global__ __launch_bounds__(256) void k_escore(const bf16_t* __restrict__ ke,
                                                const float* __restrict__ hallF,
                                                float* __restrict__ expE)
{
    const int t = blockIdx.x >> 4, b = blockIdx.x & 15;
    const int tid = threadIdx.x;
    __shared__ float hS[DIM];
    hS[tid] = hallF[(size_t)(t*BS + b)*DIM + tid];
    __syncthreads();
    for (int s = tid; s < SRC; s += 256) {
        const v8bf* kp = (const v8bf*)(ke + ((size_t)s*BS + b)*DIM);
        float e = 0.f;
#pragma unroll 8
        for (int m=0;m<32;m++) {
            v8bf kv = kp[m];
#pragma unroll
            for (int i=0;i<8;i++) e += (float)kv[i]*hS[m*8+i];
        }
        expE[((size_t)t*BS + b)*SRC + s] = __expf(e);
    }
}

// ---------------- per-(t,b) attention tail ----------------
__global__ __launch_bounds__(256) void k_attn2(
    const float* __restrict__ expE, const bf16_t* __restrict__ heT,
    const float* __restrict__ hallF, const bf16_t* __restrict__ qdG,
    const float* __restrict__ wu, const float* __restrict__ bu,
    bf16_t* __restrict__ feat, float* __restrict__ Ae, float* __restrict__ ps)
{
    const int t = blockIdx.x >> 4, b = blockIdx.x & 15;
    const int tid = threadIdx.x;
    __shared__ float hS[DIM], qdS[DIM], eeS[SRC], adS[TGT];
    __shared__ float red[4], misc[2];

    hS[tid]  = hallF[(size_t)(t*BS + b)*DIM + tid];
    qdS[tid] = (float)qdG[(size_t)(t*BS + b)*DIM + tid];
    __syncthreads();

    for (int s = tid; s < SRC; s += 256) {
        float prev = 0.f;
        for (int tp = 0; tp < t; ++tp) prev += expE[((size_t)tp*BS + b)*SRC + s];
        float my = expE[((size_t)t*BS + b)*SRC + s];
        eeS[s] = (t == 0) ? my : my / prev;
    }
    __syncthreads();
    {   // esum
        float pa = 0.f;
        for (int s = tid; s < SRC; s += 256) pa += eeS[s];
#pragma unroll
        for (int o=32;o>0;o>>=1) pa += __shfl_down(pa, o);
        if ((tid & 63) == 0) red[tid>>6] = pa;
        __syncthreads();
        if (tid == 0) misc[0] = 1.f/(red[0]+red[1]+red[2]+red[3]);
        __syncthreads();
    }
    const float inv_es = misc[0];
    for (int s = tid; s < SRC; s += 256)
        Ae[((size_t)t*BS + b)*SRC + s] = eeS[s] * inv_es;

    float ce;
    {
        const v8bf* hp = (const v8bf*)(heT + ((size_t)b*DIM + tid)*SRC);
        float acc = 0.f;
#pragma unroll 10
        for (int m=0;m<50;m++) {
            v8bf hv = hp[m];
#pragma unroll
            for (int i=0;i<8;i++) acc += (float)hv[i]*eeS[m*8+i];
        }
        ce = acc * inv_es;
    }

    {
        const int wv = tid >> 6, ln = tid & 63;
        for (int tau = wv; tau <= t; tau += 4) {
            float4 a = *(const float4*)(hallF + ((size_t)(tau*BS + b))*DIM + ln*4);
            float e = a.x*qdS[ln*4] + a.y*qdS[ln*4+1] + a.z*qdS[ln*4+2] + a.w*qdS[ln*4+3];
#pragma unroll
            for (int o=32;o>0;o>>=1) e += __shfl_down(e, o);
            if (ln == 0) adS[tau] = __expf(e);
        }
    }
    __syncthreads();
    if (tid < 64) {
        float v = (tid <= t) ? adS[tid] : 0.f;
#pragma unroll
        for (int o=32;o>0;o>>=1) v += __shfl_down(v, o);
        if (tid == 0) misc[1] = 1.f/v;
    }
    __syncthreads();
    float cd = 0.f;
    for (int tau = 0; tau <= t; ++tau)
        cd += adS[tau] * hallF[((size_t)(tau*BS + b))*DIM + tid];
    cd *= misc[1];
    if (t == 0) cd = 0.f;

    const float hd = hS[tid];
    const size_t fr = ((size_t)t*BS + b)*768;
    feat[fr + tid]       = (bf16_t)hd;
    feat[fr + 256 + tid] = (bf16_t)ce;
    feat[fr + 512 + tid] = (bf16_t)cd;
    float pw = hd*wu[tid] + ce*wu[256 + tid] + cd*wu[512 + tid];
#pragma unroll
    for (int o=32;o>0;o>>=1) pw += __shfl_down(pw, o);
    if ((tid & 63) == 0) red[tid>>6] = pw;
    __syncthreads();
    if (tid == 0) {
        float s = red[0]+red[1]+red[2]+red[3];
        ps[t*BS + b] = 1.f/(1.f+__expf(-(s + bu[0])));
    }
}

// ---------------- scale[r] = ps[r] / rowsum[r] (sums from GEMM epilogue) --------
__global__ void k_scale(const float* __restrict__ rsum, const float* __restrict__ ps,
                        float* __restrict__ scale)
{
    const int r = threadIdx.x;
    if (r < NROW) scale[r] = ps[r] / rsum[r];
}

// ---------------- scores = exp_logits * scale[r] ----------------
__global__ void k_norm(float* __restrict__ out, const float* __restrict__ scale)
{
    const long n4 = (long)NROW*VOCABN/4;
    for (long i = (long)blockIdx.x*blockDim.x + threadIdx.x; i < n4;
         i += (long)gridDim.x*blockDim.x) {
        const long r = (i*4)/VOCABN;
        float4 v = ((float4*)out)[i];
        const float sc = scale[r];
        v.x*=sc; v.y*=sc; v.z*=sc; v.w*=sc;
        ((float4*)out)[i] = v;
    }
}

// ---------------- copy mechanism scatter ----------------
__global__ __launch_bounds__(256) void k_copy(float* __restrict__ out,
                                              const int* __restrict__ src,
                                              const float* __restrict__ Ae,
                                              const float* __restrict__ ps)
{
    const int r = blockIdx.x;        // r = t*BS + b
    const int b = r & (BS-1);
    const float p = ps[r];
    for (int s = threadIdx.x; s < SRC; s += 256) {
        const int v = src[s*BS + b];
        atomicAdd(&out[(size_t)r*VOCABN + v], Ae[(size_t)r*SRC + s] * p);
    }
}

// ---------------- workspace layout (bytes, 16B-aligned) ----------------
#define O_WHH    0u
#define O_WADT   524288u
#define O_HEBF   655360u
#define O_HET    3932160u
#define O_KE     7208960u
#define O_WAE    10485760u
#define O_WPROJT 10616832u
#define O_WIH    11010048u
#define O_EMBA   11534336u
#define O_WOUT   11730944u
#define O_XG     60882944u
#define O_HALLF  62455808u
#define O_HALLB  62849024u
#define O_QD     63045632u
#define O_EXPE   63242240u
#define O_FEAT   63856640u
#define O_AE     64446464u
#define O_PS     65060864u
#define O_SCALE  65062400u
#define O_RSUM   65063936u   // 1536 B, zeroed each call

extern "C" void kernel_launch(void* const* d_in, const int* in_sizes, int n_in,
                              void* d_out, int out_size, void* d_ws, size_t ws_size,
                              hipStream_t stream)
{
    const int*   inputs = (const int*)  d_in[0];
    const int*   src    = (const int*)  d_in[1];
    const float* h_e    = (const float*)d_in[2];
    const float* h0     = (const float*)d_in[3];
    const float* c0     = (const float*)d_in[4];
    const float* W_emb  = (const float*)d_in[5];
    const float* W_ih   = (const float*)d_in[6];
    const float* b_ih   = (const float*)d_in[7];
    const float* W_hh   = (const float*)d_in[8];
    const float* b_hh   = (const float*)d_in[9];
    const float* W_ae   = (const float*)d_in[10];
    const float* W_ad   = (const float*)d_in[11];
    const float* W_proj = (const float*)d_in[12];
    const float* W_u    = (const float*)d_in[13];
    const float* b_u    = (const float*)d_in[14];
    const float* b_out  = (const float*)d_in[15];
    const int*   pad_id = (const int*)  d_in[16];

    char* w = (char*)d_ws;
    bf16_t* whh_bf  = (bf16_t*)(w + O_WHH);
    bf16_t* wadT_bf = (bf16_t*)(w + O_WADT);
    bf16_t* he_bf   = (bf16_t*)(w + O_HEBF);
    bf16_t* heT_bf  = (bf16_t*)(w + O_HET);
    bf16_t* ke_bf   = (bf16_t*)(w + O_KE);
    bf16_t* wae_bf  = (bf16_t*)(w + O_WAE);
    bf16_t* wprojT  = (bf16_t*)(w + O_WPROJT);
    bf16_t* wih_bf  = (bf16_t*)(w + O_WIH);
    bf16_t* embA_bf = (bf16_t*)(w + O_EMBA);
    bf16_t* wout_bf = (bf16_t*)(w + O_WOUT);
    float*  xg      = (float*) (w + O_XG);
    float*  hallF   = (float*) (w + O_HALLF);
    bf16_t* hallB   = (bf16_t*)(w + O_HALLB);
    bf16_t* qdG     = (bf16_t*)(w + O_QD);
    float*  expE    = (float*) (w + O_EXPE);
    bf16_t* feat_bf = (bf16_t*)(w + O_FEAT);
    float*  Ae      = (float*) (w + O_AE);
    float*  ps      = (float*) (w + O_PS);
    float*  scale   = (float*) (w + O_SCALE);
    float*  rsum    = (float*) (w + O_RSUM);
    float*  out     = (float*)d_out;

    k_prep<<<1024, 256, 0, stream>>>(W_hh, W_ad, h_e, W_emb, W_proj, W_ae, W_ih, inputs,
                                     whh_bf, wadT_bf, he_bf, heT_bf,
                                     wae_bf, wih_bf, wprojT, embA_bf);
    hipMemsetAsync(w + O_RSUM, 0, 1536, stream);
    // xg = embA @ W_ih^T + b_ih + b_hh        (M=384, N=1024, K=256)
    k_gemm<<<24, 256, 0, stream>>>(embA_bf, nullptr, wih_bf, 1024, 256, 8, 0,
                                   xg, nullptr, b_ih, b_hh, nullptr, nullptr);
    // fused: LSTM chain (block 0) + W_out GEMM (1..1500) + ke GEMM (1501..1600)
    k_fused<<<1601, 256, 0, stream>>>(whh_bf, xg, h0, c0, hallF, hallB,
                                      W_emb, wprojT, wout_bf,
                                      he_bf, wae_bf, ke_bf);
    // qd = h_all @ W_attn_dec                 (M=384, N=256, K=256)
    k_gemm<<<6, 256, 0, stream>>>(hallB, nullptr, wadT_bf, 256, 256, 2, 2,
                                  nullptr, qdG, nullptr, nullptr, nullptr, nullptr);
    // parallel attention tail
    k_escore<<<NROW, 256, 0, stream>>>(ke_bf, hallF, expE);
    k_attn2<<<NROW, 256, 0, stream>>>(expE, heT_bf, hallF, qdG, W_u, b_u,
                                      feat_bf, Ae, ps);
    // exp(logits + b_out), pad -> 0, + fused row sums  (M=384, N=32000, K=768)
    k_gemm<<<750, 256, 0, stream>>>(feat_bf, nullptr, wout_bf, VOCABN, 768, 250, 3,
                                    out, nullptr, b_out, nullptr, pad_id, rsum);
    k_scale<<<1, 384, 0, stream>>>(rsum, ps, scale);
    k_norm<<<2048, 256, 0, stream>>>(out, scale);
    k_copy<<<NROW, 256, 0, stream>>>(out, src, Ae, ps);
}